// Round 14
// baseline (246.592 us; speedup 1.0000x reference)
//
#include <hip/hip_runtime.h>

// Problem constants (match reference)
#define BATCH 8192
#define TSTEPS 200
#define FEAT 16
#define HID 32
#define GATES 128   // 4*HID, Keras order: i | f | cc | o
#define DOUT 60
#define ROWS 16     // batch rows per tile (one MFMA N-tile)
#define HSTRIDE 40  // LDS h row stride in halves (80 B)
#define NL2E -1.44269504088896340736f

typedef __fp16 half2v __attribute__((ext_vector_type(2)));
typedef __fp16 half4v __attribute__((ext_vector_type(4)));
typedef __fp16 half8v __attribute__((ext_vector_type(8)));
typedef float  float2v __attribute__((ext_vector_type(2)));
typedef float  float4v __attribute__((ext_vector_type(4)));

__device__ __forceinline__ half2v pkrtz(float a, float b) {
    return __builtin_amdgcn_cvt_pkrtz(a, b);
}

__device__ __forceinline__ half4v pack4(float4 v) {
    half2v lo = pkrtz(v.x, v.y);
    half2v hi = pkrtz(v.z, v.w);
    half4v r;
    r[0] = lo[0]; r[1] = lo[1]; r[2] = hi[0]; r[3] = hi[1];
    return r;
}

// Wave barrier WITHOUT the vmcnt drain (verified R11/R12). lgkmcnt(0)
// orders this wave's ds_write/ds_read around s_barrier; x prefetch (VMEM)
// stays in flight across it.
__device__ __forceinline__ void lds_barrier() {
    __builtin_amdgcn_sched_barrier(0);
    asm volatile("s_waitcnt lgkmcnt(0)\n\ts_barrier" ::: "memory");
    __builtin_amdgcn_sched_barrier(0);
}

// R14 = R12's verified 4-wave gate-split team x TWO independent batch tiles
// per wave. R13 taught that same-block waves are barrier-lockstep and can't
// fill each other's stalls; R14 fills the ~50% SIMD idle with per-wave ILP
// from a second independent recurrence chain instead (stationary U/W/bias
// fragments shared between tiles; only acc/accx/cst/x-prefetch duplicate).
// Wave w (0..3) owns h-units [8w, 8w+8) of BOTH tiles; column permutation,
// fragment layouts, and epilogue math identical to R12 (bit-identical
// numerics, absmax 0.001953125):
//   tile tt2 rows m: gate 2*tt2 + ((m&3)>>1), unit 8w + 2*(m>>2) + (m&1)
//   gates i,f,o prescaled by -log2(e); num = c*d_i + relu(cc)*d_f;
//   ee = d_i*d_f*d_o; c' = num*(ie*d_o); h = relu(num)*ie; one rcp/pair.
// 256 blocks x 4 waves = 1024 waves = 1/SIMD; each wave's two chains
// interleave in the compiler-scheduled monolithic body (R4/R6/R7 lesson).
__device__ __forceinline__ void epi(
    const float4v& acc0, const float4v& acc1, float2v& cst,
    __fp16* hw, int hwoff)
{
    const float2v one  = {1.0f, 1.0f};
    const float2v zero = {0.0f, 0.0f};
    float2v ei, ef, eo;
    ei[0] = __builtin_amdgcn_exp2f(acc0[0]);
    ei[1] = __builtin_amdgcn_exp2f(acc0[1]);
    ef[0] = __builtin_amdgcn_exp2f(acc0[2]);
    ef[1] = __builtin_amdgcn_exp2f(acc0[3]);
    eo[0] = __builtin_amdgcn_exp2f(acc1[2]);
    eo[1] = __builtin_amdgcn_exp2f(acc1[3]);
    float2v di  = one + ei;
    float2v df  = one + ef;
    float2v dov = one + eo;
    float2v cc2 = {acc1[0], acc1[1]};
    float2v rc  = __builtin_elementwise_max(cc2, zero);
    float2v num = __builtin_elementwise_fma(cst, di, rc * df);
    float2v ee  = (di * df) * dov;
    float   Q   = __builtin_amdgcn_rcpf(ee[0] * ee[1]);
    float2v ie  = {Q * ee[1], Q * ee[0]};
    cst = num * (ie * dov);
    float2v h2  = __builtin_elementwise_max(num, zero) * ie;
    *reinterpret_cast<half2v*>(&hw[hwoff]) = pkrtz(h2[0], h2[1]);
}

template <bool DO_XW, bool DO_LOAD, int LOFF>
__device__ __forceinline__ void lstm_step2(
    float4& XNa, float4& XNb, const float* xpa, const float* xpb,
    const half8v (&aU)[2], const half4v (&aW)[2], const float4v (&bias)[2],
    float4v (&accxA)[2], float4v (&accxB)[2], float2v& cstA, float2v& cstB,
    const __fp16* hrA, __fp16* hwA, const __fp16* hrB, __fp16* hwB,
    int hroff, int hwoff)
{
    half8v hA = *reinterpret_cast<const half8v*>(&hrA[hroff]);
    half8v hB = *reinterpret_cast<const half8v*>(&hrB[hroff]);

    float4v accA0 = __builtin_amdgcn_mfma_f32_16x16x32_f16(
        aU[0], hA, accxA[0], 0, 0, 0);
    float4v accA1 = __builtin_amdgcn_mfma_f32_16x16x32_f16(
        aU[1], hA, accxA[1], 0, 0, 0);
    float4v accB0 = __builtin_amdgcn_mfma_f32_16x16x32_f16(
        aU[0], hB, accxB[0], 0, 0, 0);
    float4v accB1 = __builtin_amdgcn_mfma_f32_16x16x32_f16(
        aU[1], hB, accxB[1], 0, 0, 0);

    if (DO_XW) {
        half4v axA = pack4(XNa);
        half4v axB = pack4(XNb);
        accxA[0] = __builtin_amdgcn_mfma_f32_16x16x16f16(
            aW[0], axA, bias[0], 0, 0, 0);
        accxA[1] = __builtin_amdgcn_mfma_f32_16x16x16f16(
            aW[1], axA, bias[1], 0, 0, 0);
        accxB[0] = __builtin_amdgcn_mfma_f32_16x16x16f16(
            aW[0], axB, bias[0], 0, 0, 0);
        accxB[1] = __builtin_amdgcn_mfma_f32_16x16x16f16(
            aW[1], axB, bias[1], 0, 0, 0);
    }
    if (DO_LOAD) {
        XNa = *reinterpret_cast<const float4*>(xpa + LOFF);
        XNb = *reinterpret_cast<const float4*>(xpb + LOFF);
    }

    // Two independent epilogues -- compiler interleaves their dep chains.
    epi(accA0, accA1, cstA, hwA, hwoff);
    epi(accB0, accB1, cstB, hwB, hwoff);

    lds_barrier();   // LDS-only sync: x loads stay in flight (no vmcnt drain)
}

__global__ __launch_bounds__(256, 1) void lstm_mfma(
    const float* __restrict__ x,    // [B, T, F]
    const float* __restrict__ W,    // [F, 128]
    const float* __restrict__ U,    // [H, 128]
    const float* __restrict__ bg,   // [128]
    const float* __restrict__ W1,   // [H, 60]
    const float* __restrict__ b1,   // [60]
    const float* __restrict__ W2,   // [H, 60]
    const float* __restrict__ b2,   // [60]
    float* __restrict__ out)        // [2 * B * 60] (long || lat)
{
    const int tid  = threadIdx.x;   // 256 threads = 4 waves
    const int lane = tid & 63;
    const int w    = tid >> 6;      // unit-octet: 0..3
    const int n16  = lane & 15;     // batch row within tile
    const int g    = lane >> 4;     // k-quad / D-row-quad
    const int b0   = blockIdx.x * (2 * ROWS);

    __shared__ __align__(16) __fp16 hbuf[2][2][ROWS * HSTRIDE]; // [buf][tile]

    // ---- stationary A-frags (shared by both tiles): U^T, W^T, bias ----
    // Column map (tile tt2, D row m): gate = 2*tt2 + ((m&3)>>1);
    // col = 32*gate + 8*w + 2*(m>>2) + (m&1); scale 1.0 for cc, -log2e else.
    half8v  aU[2];
    half4v  aW[2];
    float4v bias[2];
    #pragma unroll
    for (int tt2 = 0; tt2 < 2; tt2++) {
        const int gA   = 2 * tt2 + ((n16 >> 1) & 1);       // gate of A column
        const float sA = (gA == 2) ? 1.0f : NL2E;
        const int colA = 32 * gA + 8 * w + 2 * (n16 >> 2) + (n16 & 1);
        half8v u8;
        #pragma unroll
        for (int j = 0; j < 8; j++)
            u8[j] = (__fp16)(U[(8 * g + j) * GATES + colA] * sA);
        aU[tt2] = u8;
        half4v w4;
        #pragma unroll
        for (int j = 0; j < 4; j++)
            w4[j] = (__fp16)(W[(4 * g + j) * GATES + colA] * sA);
        aW[tt2] = w4;
        float4v bv;
        #pragma unroll
        for (int r = 0; r < 4; r++) {
            const int gi = 2 * tt2 + (r >> 1);
            const int cb = 32 * gi + 8 * w + 2 * g + (r & 1);
            bv[r] = bg[cb] * ((gi == 2) ? 1.0f : NL2E);
        }
        bias[tt2] = bv;
    }

    // zero h_0 buffers (both tiles)
    for (int i = tid; i < 2 * ROWS * HSTRIDE; i += 256)
        hbuf[0][0][i] = (__fp16)0.f;

    // x sources: tile A rows b0+n16, tile B rows b0+16+n16
    const float* xrowA = x + (size_t)(b0 + n16) * TSTEPS * FEAT + 4 * g;
    const float* xrowB = x + (size_t)(b0 + ROWS + n16) * TSTEPS * FEAT + 4 * g;

    float4 xa0 = *reinterpret_cast<const float4*>(xrowA + FEAT);       // x_1
    float4 xa1 = *reinterpret_cast<const float4*>(xrowA + 2 * FEAT);   // x_2
    float4 xb0 = *reinterpret_cast<const float4*>(xrowB + FEAT);
    float4 xb1 = *reinterpret_cast<const float4*>(xrowB + 2 * FEAT);

    // accx(0) = bias + W^T·x_0^T for both tiles
    float4v accxA[2], accxB[2];
    {
        half4v a0 = pack4(*reinterpret_cast<const float4*>(xrowA));
        half4v b0v = pack4(*reinterpret_cast<const float4*>(xrowB));
        accxA[0] = __builtin_amdgcn_mfma_f32_16x16x16f16(
            aW[0], a0, bias[0], 0, 0, 0);
        accxA[1] = __builtin_amdgcn_mfma_f32_16x16x16f16(
            aW[1], a0, bias[1], 0, 0, 0);
        accxB[0] = __builtin_amdgcn_mfma_f32_16x16x16f16(
            aW[0], b0v, bias[0], 0, 0, 0);
        accxB[1] = __builtin_amdgcn_mfma_f32_16x16x16f16(
            aW[1], b0v, bias[1], 0, 0, 0);
    }

    float2v cstA = {0.f, 0.f}, cstB = {0.f, 0.f};
    const int hroff = n16 * HSTRIDE + 8 * g;           // B-frag read (16B)
    const int hwoff = n16 * HSTRIDE + 8 * w + 2 * g;   // h write (4B, half2)

    __syncthreads();   // h_0 zero-init visible (once; drain cost negligible)

    // Branch-free main loop: steps 0..195. Step t reads hbuf[t&1][*], writes
    // hbuf[(t+1)&1][*]. Invariant: x*0 = x_{t+1}, x*1 = x_{t+2}, xp* = &x_t.
    const float* xpa = xrowA;
    const float* xpb = xrowB;
    for (int it = 0; it < (TSTEPS - 4) / 2; ++it) {
        lstm_step2<true, true, 3 * FEAT>(xa0, xb0, xpa, xpb, aU, aW, bias,
            accxA, accxB, cstA, cstB,
            hbuf[0][0], hbuf[1][0], hbuf[0][1], hbuf[1][1], hroff, hwoff);
        lstm_step2<true, true, 4 * FEAT>(xa1, xb1, xpa, xpb, aU, aW, bias,
            accxA, accxB, cstA, cstB,
            hbuf[1][0], hbuf[0][0], hbuf[1][1], hbuf[0][1], hroff, hwoff);
        xpa += 2 * FEAT;
        xpb += 2 * FEAT;
    }
    // Peeled tail: steps 196..199 (xp* == &x_196; x*0=x_197, x*1=x_198)
    lstm_step2<true, true, 3 * FEAT>(xa0, xb0, xpa, xpb, aU, aW, bias,
        accxA, accxB, cstA, cstB,
        hbuf[0][0], hbuf[1][0], hbuf[0][1], hbuf[1][1], hroff, hwoff); // 196
    lstm_step2<true, false, 0>(xa1, xb1, xpa, xpb, aU, aW, bias,
        accxA, accxB, cstA, cstB,
        hbuf[1][0], hbuf[0][0], hbuf[1][1], hbuf[0][1], hroff, hwoff); // 197
    lstm_step2<true, false, 0>(xa0, xb0, xpa, xpb, aU, aW, bias,
        accxA, accxB, cstA, cstB,
        hbuf[0][0], hbuf[1][0], hbuf[0][1], hbuf[1][1], hroff, hwoff); // 198
    lstm_step2<false, false, 0>(xa1, xb1, xpa, xpb, aU, aW, bias,
        accxA, accxB, cstA, cstB,
        hbuf[1][0], hbuf[0][0], hbuf[1][1], hbuf[0][1], hroff, hwoff); // 199

    // h_T lives in hbuf[0][tile]; step 199's lds_barrier covers the reads.
    // ---- heads: out = h_T @ W1/W2 + b (fp32, h from LDS, 256 threads) ----
    for (int idx = tid; idx < 2 * ROWS * DOUT; idx += 256) {
        const int row = idx / DOUT;          // 0..31
        const int d   = idx - row * DOUT;
        const __fp16* hf = &hbuf[0][row >> 4][(row & 15) * HSTRIDE];
        float s1 = b1[d], s2 = b2[d];
        #pragma unroll 8
        for (int k = 0; k < HID; k++) {
            float hv = (float)hf[k];
            s1 = fmaf(hv, W1[k * DOUT + d], s1);
            s2 = fmaf(hv, W2[k * DOUT + d], s2);
        }
        out[(size_t)(b0 + row) * DOUT + d] = s1;
        out[(size_t)BATCH * DOUT + (size_t)(b0 + row) * DOUT + d] = s2;
    }
}

extern "C" void kernel_launch(void* const* d_in, const int* in_sizes, int n_in,
                              void* d_out, int out_size, void* d_ws, size_t ws_size,
                              hipStream_t stream) {
    const float* x  = (const float*)d_in[0];
    const float* W  = (const float*)d_in[1];
    const float* U  = (const float*)d_in[2];
    const float* bg = (const float*)d_in[3];
    const float* W1 = (const float*)d_in[4];
    const float* b1 = (const float*)d_in[5];
    const float* W2 = (const float*)d_in[6];
    const float* b2 = (const float*)d_in[7];
    float* out = (float*)d_out;

    dim3 grid(BATCH / (2 * ROWS));   // 256 blocks x 4 waves, 2 tiles/wave
    dim3 block(256);
    lstm_mfma<<<grid, block, 0, stream>>>(x, W, U, bg, W1, b1, W2, b2, out);
}